// Round 3
// baseline (742.391 us; speedup 1.0000x reference)
//
#include <hip/hip_runtime.h>
#include <hip/hip_bf16.h>

#define TT 2048
#define DM 2048
#define NH 16
#define KVH 4
#define HD 128

typedef __attribute__((ext_vector_type(8))) short bs8;
typedef __attribute__((ext_vector_type(4))) float fx4;
typedef __attribute__((ext_vector_type(4))) unsigned short us4;

__device__ inline unsigned short f2b(float f) {
  __hip_bfloat16 h = __float2bfloat16(f);
  return *reinterpret_cast<unsigned short*>(&h);
}

__device__ inline void gld_lds16(const ushort* g, ushort* l) {
  __builtin_amdgcn_global_load_lds(
      (const __attribute__((address_space(1))) void*)g,
      (__attribute__((address_space(3))) void*)l,
      16, 0, 0);
}

// ---------------- cast x: fp32 -> bf16, 4 elems/thread ----------------
__global__ __launch_bounds__(256) void cast_f32_bf16(const float* __restrict__ in,
                                                     ushort* __restrict__ out) {
  int i = blockIdx.x * 256 + threadIdx.x;
  float4 v = ((const float4*)in)[i];
  us4 o = {f2b(v.x), f2b(v.y), f2b(v.z), f2b(v.w)};
  ((us4*)out)[i] = o;
}

// ---------------- fused transpose+cast of all weights ----------------
// z=0: Wqkvt[3072][2048] from Wq|Wk|Wv   z=1: Wot[2048][2048] from Wo
__global__ __launch_bounds__(256) void transpose_cast_all(
    const float* __restrict__ Wq, const float* __restrict__ Wk,
    const float* __restrict__ Wv, const float* __restrict__ Wo,
    ushort* __restrict__ Wqkvt, ushort* __restrict__ Wot) {
  __shared__ float t[32][33];
  int tx = threadIdx.x, ty = threadIdx.y;  // block (32,8)
  int n0 = blockIdx.x * 32, k0 = blockIdx.y * 32;
  if (blockIdx.z == 0) {
    const float* src;
    int srcN, col0;
    if (n0 < 2048) { src = Wq; srcN = 2048; col0 = n0; }
    else if (n0 < 2560) { src = Wk; srcN = 512; col0 = n0 - 2048; }
    else { src = Wv; srcN = 512; col0 = n0 - 2560; }
    for (int jj = 0; jj < 4; ++jj)
      t[ty + jj * 8][tx] = src[(size_t)(k0 + ty + jj * 8) * srcN + col0 + tx];
    __syncthreads();
    for (int jj = 0; jj < 4; ++jj)
      Wqkvt[(size_t)(n0 + ty + jj * 8) * 2048 + k0 + tx] = f2b(t[tx][ty + jj * 8]);
  } else {
    if (n0 >= 2048) return;
    for (int jj = 0; jj < 4; ++jj)
      t[ty + jj * 8][tx] = Wo[(size_t)(k0 + ty + jj * 8) * 2048 + n0 + tx];
    __syncthreads();
    for (int jj = 0; jj < 4; ++jj)
      Wot[(size_t)(n0 + ty + jj * 8) * 2048 + k0 + tx] = f2b(t[tx][ty + jj * 8]);
  }
}

// ---------------- fused QKV GEMM: [4096 x 3072] = xb * Wqkvt^T ----------------
// epilogue routes by n-block: [0,2048)->q rowmajor, [2048,2560)->k [b,g,t,d],
// [2560,3072)->v transposed [b,g,d,t]
__global__ __launch_bounds__(256) void gemm_qkv(const ushort* __restrict__ A,
                                                const ushort* __restrict__ Bt,
                                                ushort* __restrict__ qo,
                                                ushort* __restrict__ ko,
                                                ushort* __restrict__ vo,
                                                int K) {
  __shared__ alignas(16) ushort As[128 * 64];
  __shared__ alignas(16) ushort Bs[128 * 64];
  const int tid = threadIdx.x;
  const int lane = tid & 63;
  const int wid = tid >> 6;
  const int wm = wid >> 1, wn = wid & 1;
  const int quad = lane >> 4, l16 = lane & 15;
  const int bm = blockIdx.y * 128, bn = blockIdx.x * 128;

  fx4 acc[4][4];
  for (int i = 0; i < 4; ++i)
    for (int j = 0; j < 4; ++j) acc[i][j] = (fx4){0.f, 0.f, 0.f, 0.f};

  const int r8 = lane >> 3, s8 = lane & 7;
  for (int k0 = 0; k0 < K; k0 += 64) {
    for (int i = 0; i < 4; ++i) {
      int m = i * 32 + wid * 8 + r8;
      int c = s8 ^ (m & 7);
      gld_lds16(A + (size_t)(bm + m) * K + k0 + c * 8, As + (i * 32 + wid * 8) * 64);
      gld_lds16(Bt + (size_t)(bn + m) * K + k0 + c * 8, Bs + (i * 32 + wid * 8) * 64);
    }
    __syncthreads();
    for (int ks = 0; ks < 2; ++ks) {
      bs8 af[4], bf[4];
      for (int mt = 0; mt < 4; ++mt) {
        int m = wm * 64 + mt * 16 + l16;
        int c = ks * 4 + quad;
        int slot = c ^ (m & 7);
        af[mt] = *(const bs8*)(As + m * 64 + slot * 8);
      }
      for (int nt = 0; nt < 4; ++nt) {
        int n = wn * 64 + nt * 16 + l16;
        int c = ks * 4 + quad;
        int slot = c ^ (n & 7);
        bf[nt] = *(const bs8*)(Bs + n * 64 + slot * 8);
      }
      for (int mt = 0; mt < 4; ++mt)
        for (int nt = 0; nt < 4; ++nt)
          acc[mt][nt] = __builtin_amdgcn_mfma_f32_16x16x32_bf16(af[mt], bf[nt],
                                                                acc[mt][nt], 0, 0, 0);
    }
    __syncthreads();
  }

  for (int mt = 0; mt < 4; ++mt)
    for (int nt = 0; nt < 4; ++nt)
      for (int r = 0; r < 4; ++r) {
        int row = bm + wm * 64 + mt * 16 + quad * 4 + r;
        int col = bn + wn * 64 + nt * 16 + l16;
        float v = acc[mt][nt][r];
        if (bn < 2048) {
          qo[(size_t)row * 2048 + col] = f2b(v);
        } else if (bn < 2560) {
          int kc = col - 2048;
          int b = row >> 11, t = row & 2047;
          int gg = kc >> 7, d = kc & 127;
          ko[((size_t)(b * KVH + gg) * TT + t) * HD + d] = f2b(v);
        } else {
          int vc = col - 2560;
          int b = row >> 11, t = row & 2047;
          int gg = vc >> 7, d = vc & 127;
          vo[((size_t)(b * KVH + gg) * HD + d) * TT + t] = f2b(v);
        }
      }
}

// ---------------- output-projection GEMM: fp32 out ----------------
__global__ __launch_bounds__(256) void gemm_out(const ushort* __restrict__ A,
                                                const ushort* __restrict__ Bt,
                                                float* __restrict__ Cout,
                                                int N, int K) {
  __shared__ alignas(16) ushort As[128 * 64];
  __shared__ alignas(16) ushort Bs[128 * 64];
  const int tid = threadIdx.x;
  const int lane = tid & 63;
  const int wid = tid >> 6;
  const int wm = wid >> 1, wn = wid & 1;
  const int quad = lane >> 4, l16 = lane & 15;
  const int bm = blockIdx.y * 128, bn = blockIdx.x * 128;

  fx4 acc[4][4];
  for (int i = 0; i < 4; ++i)
    for (int j = 0; j < 4; ++j) acc[i][j] = (fx4){0.f, 0.f, 0.f, 0.f};

  const int r8 = lane >> 3, s8 = lane & 7;
  for (int k0 = 0; k0 < K; k0 += 64) {
    for (int i = 0; i < 4; ++i) {
      int m = i * 32 + wid * 8 + r8;
      int c = s8 ^ (m & 7);
      gld_lds16(A + (size_t)(bm + m) * K + k0 + c * 8, As + (i * 32 + wid * 8) * 64);
      gld_lds16(Bt + (size_t)(bn + m) * K + k0 + c * 8, Bs + (i * 32 + wid * 8) * 64);
    }
    __syncthreads();
    for (int ks = 0; ks < 2; ++ks) {
      bs8 af[4], bf[4];
      for (int mt = 0; mt < 4; ++mt) {
        int m = wm * 64 + mt * 16 + l16;
        int c = ks * 4 + quad;
        int slot = c ^ (m & 7);
        af[mt] = *(const bs8*)(As + m * 64 + slot * 8);
      }
      for (int nt = 0; nt < 4; ++nt) {
        int n = wn * 64 + nt * 16 + l16;
        int c = ks * 4 + quad;
        int slot = c ^ (n & 7);
        bf[nt] = *(const bs8*)(Bs + n * 64 + slot * 8);
      }
      for (int mt = 0; mt < 4; ++mt)
        for (int nt = 0; nt < 4; ++nt)
          acc[mt][nt] = __builtin_amdgcn_mfma_f32_16x16x32_bf16(af[mt], bf[nt],
                                                                acc[mt][nt], 0, 0, 0);
    }
    __syncthreads();
  }

  for (int mt = 0; mt < 4; ++mt)
    for (int nt = 0; nt < 4; ++nt)
      for (int r = 0; r < 4; ++r) {
        int row = bm + wm * 64 + mt * 16 + quad * 4 + r;
        int col = bn + wn * 64 + nt * 16 + l16;
        Cout[(size_t)row * N + col] = acc[mt][nt][r];
      }
}

// ---------------- fused causal WGQA attention, pair-balanced ----------------
// grid = 512: bid -> (b, h, pair p). Block handles 64-q chunks cA=p and cB=31-p.
// Each wave owns 16 queries of each chunk (nt=0 -> cA, nt=1 -> cB).
// Total MFMA work per block is uniform (33 key-tile equivalents).
__global__ __launch_bounds__(256) void attn_kernel(const ushort* __restrict__ qb,
                                                   const ushort* __restrict__ kb,
                                                   const ushort* __restrict__ vt,
                                                   ushort* __restrict__ yb,
                                                   const float* __restrict__ wlog) {
  __shared__ alignas(16) ushort Ks[64 * 128];   // [key][d], chunk-swizzled
  __shared__ alignas(16) ushort Vs[128 * 64];   // [d][key], chunk-swizzled
  __shared__ alignas(16) ushort Ps[128 * 72];   // [q][key], stride 72 (pad)

  const int bid = blockIdx.x;
  const int p = bid & 15;
  const int h = (bid >> 4) & 15;
  const int b = bid >> 8;
  const int g = h >> 2;
  const int tid = threadIdx.x;
  const int lane = tid & 63;
  const int wid = tid >> 6;
  const int quad = lane >> 4;
  const int l16 = lane & 15;

  const int cA = p;        // short chunk: needs key-tiles 0..cA
  const int cB = 31 - p;   // long chunk:  needs key-tiles 0..cB
  const int qA = cA * 64 + wid * 16 + l16;
  const int qB = cB * 64 + wid * 16 + l16;

  const float scale = wlog[g] * 0.08838834764831845f;  // 1/sqrt(128)

  // Q fragments in registers (B-operand of S^T = K * Q^T); nt=0 -> cA, nt=1 -> cB
  bs8 qf[2][4];
  for (int nt = 0; nt < 2; ++nt) {
    int q = nt ? qB : qA;
    const ushort* qrow = qb + ((size_t)(b * TT + q)) * DM + h * HD;
    for (int ks = 0; ks < 4; ++ks)
      qf[nt][ks] = *(const bs8*)(qrow + ks * 32 + quad * 8);
  }

  float m_i[2] = {-INFINITY, -INFINITY};
  float l_i[2] = {0.f, 0.f};
  fx4 o[8][2];
  for (int i = 0; i < 8; ++i)
    for (int nt = 0; nt < 2; ++nt) o[i][nt] = (fx4){0.f, 0.f, 0.f, 0.f};

  const ushort* kbase = kb + (size_t)(b * KVH + g) * TT * HD;
  const ushort* vbase = vt + (size_t)(b * KVH + g) * HD * TT;

  for (int j = 0; j <= cB; ++j) {
    // ---- stage K tile (64 keys x 128 d) and V^T tile (128 d x 64 keys) ----
    {
      int r4 = lane >> 4, sidx = lane & 15;
      for (int i = 0; i < 4; ++i) {
        int key = i * 16 + wid * 4 + r4;
        int c = (sidx & 8) | ((sidx ^ key) & 7);
        gld_lds16(kbase + (size_t)(j * 64 + key) * HD + c * 8,
                  Ks + (i * 16 + wid * 4) * 128);
      }
      int r8 = lane >> 3, s8 = lane & 7;
      for (int i = 0; i < 4; ++i) {
        int d = i * 32 + wid * 8 + r8;
        int c = s8 ^ (d & 7);
        gld_lds16(vbase + (size_t)d * TT + j * 64 + c * 8,
                  Vs + (i * 32 + wid * 8) * 64);
      }
    }
    __syncthreads();

    const bool actA = (j <= cA);  // block-uniform: no divergence

    // ---- S^T = K * Q^T  (keys x queries), fp32 acc ----
    fx4 s[2][4];
    for (int nt = 0; nt < 2; ++nt)
      for (int mt = 0; mt < 4; ++mt) s[nt][mt] = (fx4){0.f, 0.f, 0.f, 0.f};
    for (int mt = 0; mt < 4; ++mt) {
      bs8 a[4];
      int key = mt * 16 + l16;
      for (int ks = 0; ks < 4; ++ks) {
        int c = ks * 4 + quad;
        int slot = (c & 8) | ((c ^ key) & 7);
        a[ks] = *(const bs8*)(Ks + key * 128 + slot * 8);
      }
      for (int ks = 0; ks < 4; ++ks)
        s[1][mt] = __builtin_amdgcn_mfma_f32_16x16x32_bf16(a[ks], qf[1][ks],
                                                           s[1][mt], 0, 0, 0);
      if (actA)
        for (int ks = 0; ks < 4; ++ks)
          s[0][mt] = __builtin_amdgcn_mfma_f32_16x16x32_bf16(a[ks], qf[0][ks],
                                                             s[0][mt], 0, 0, 0);
    }

    // ---- scale + mask + online softmax + P write ----
    for (int nt = actA ? 0 : 1; nt < 2; ++nt) {
      const int cq = nt ? cB : cA;
      const int q = nt ? qB : qA;
      const bool diag = (j == cq);
      for (int mt = 0; mt < 4; ++mt)
        for (int r = 0; r < 4; ++r) {
          float v = s[nt][mt][r] * scale;
          if (diag) {
            int key = j * 64 + mt * 16 + quad * 4 + r;
            if (key > q) v = -1e30f;
          }
          s[nt][mt][r] = v;
        }
      float mx = s[nt][0][0];
      for (int mt = 0; mt < 4; ++mt)
        for (int r = 0; r < 4; ++r) mx = fmaxf(mx, s[nt][mt][r]);
      mx = fmaxf(mx, __shfl_xor(mx, 16));
      mx = fmaxf(mx, __shfl_xor(mx, 32));
      float m_new = fmaxf(m_i[nt], mx);
      float alpha = __expf(m_i[nt] - m_new);
      float sum = 0.f;
      for (int mt = 0; mt < 4; ++mt)
        for (int r = 0; r < 4; ++r) {
          float pv = __expf(s[nt][mt][r] - m_new);
          s[nt][mt][r] = pv;
          sum += pv;
        }
      sum += __shfl_xor(sum, 16);
      sum += __shfl_xor(sum, 32);
      l_i[nt] = l_i[nt] * alpha + sum;
      m_i[nt] = m_new;
      for (int dmt = 0; dmt < 8; ++dmt)
        for (int r = 0; r < 4; ++r) o[dmt][nt][r] *= alpha;
      int qrow = wid * 32 + nt * 16 + l16;
      for (int mt = 0; mt < 4; ++mt) {
        us4 pw = {f2b(s[nt][mt][0]), f2b(s[nt][mt][1]),
                  f2b(s[nt][mt][2]), f2b(s[nt][mt][3])};
        *(us4*)(Ps + qrow * 72 + mt * 16 + quad * 4) = pw;
      }
    }

    // ---- O^T += V^T * P^T  (wave reads only its own P rows; no barrier) ----
    for (int ks = 0; ks < 2; ++ks) {
      bs8 va[8];
      for (int dmt = 0; dmt < 8; ++dmt) {
        int d = dmt * 16 + l16;
        int c = ks * 4 + quad;
        int slot = c ^ (d & 7);
        va[dmt] = *(const bs8*)(Vs + d * 64 + slot * 8);
      }
      for (int nt = actA ? 0 : 1; nt < 2; ++nt) {
        int qrow = wid * 32 + nt * 16 + l16;
        bs8 pb = *(const bs8*)(Ps + qrow * 72 + ks * 32 + quad * 8);
        for (int dmt = 0; dmt < 8; ++dmt)
          o[dmt][nt] = __builtin_amdgcn_mfma_f32_16x16x32_bf16(va[dmt], pb,
                                                               o[dmt][nt], 0, 0, 0);
      }
    }
    __syncthreads();
  }

  // ---- epilogue: normalize and write y (bf16, [b][t][h*128+d]) ----
  for (int nt = 0; nt < 2; ++nt) {
    float inv = 1.0f / l_i[nt];
    int q = nt ? qB : qA;
    ushort* yrow = yb + ((size_t)(b * TT + q)) * DM + h * HD;
    for (int dmt = 0; dmt < 8; ++dmt) {
      us4 w = {f2b(o[dmt][nt][0] * inv), f2b(o[dmt][nt][1] * inv),
               f2b(o[dmt][nt][2] * inv), f2b(o[dmt][nt][3] * inv)};
      *(us4*)(yrow + dmt * 16 + quad * 4) = w;
    }
  }
}

// ---------------- launch ----------------
extern "C" void kernel_launch(void* const* d_in, const int* in_sizes, int n_in,
                              void* d_out, int out_size, void* d_ws, size_t ws_size,
                              hipStream_t stream) {
  const float* x = (const float*)d_in[0];
  // d_in[1] = attn_mask: ignored (exact causal mask computed analytically)
  const float* Wq = (const float*)d_in[2];
  const float* Wk = (const float*)d_in[3];
  const float* Wv = (const float*)d_in[4];
  const float* Wo = (const float*)d_in[5];
  const float* wlog = (const float*)d_in[6];
  // d_in[7] = weight_values: unused by the reference

  char* ws = (char*)d_ws;
  ushort* xb = (ushort*)ws;     ws += (size_t)4096 * 2048 * 2;
  ushort* Wqkvt = (ushort*)ws;  ws += (size_t)3072 * 2048 * 2;
  ushort* Wot = (ushort*)ws;    ws += (size_t)2048 * 2048 * 2;
  ushort* qbuf = (ushort*)ws;   ws += (size_t)4096 * 2048 * 2;
  ushort* kbuf = (ushort*)ws;   ws += (size_t)2 * KVH * 2048 * 128 * 2;
  ushort* vbuf = (ushort*)ws;   ws += (size_t)2 * KVH * 2048 * 128 * 2;
  ushort* ybuf = (ushort*)ws;   ws += (size_t)4096 * 2048 * 2;

  cast_f32_bf16<<<8192, 256, 0, stream>>>(x, xb);
  transpose_cast_all<<<dim3(96, 64, 2), dim3(32, 8), 0, stream>>>(
      Wq, Wk, Wv, Wo, Wqkvt, Wot);
  gemm_qkv<<<dim3(24, 32), 256, 0, stream>>>(xb, Wqkvt, qbuf, kbuf, vbuf, 2048);
  attn_kernel<<<512, 256, 0, stream>>>(qbuf, kbuf, vbuf, ybuf, wlog);
  gemm_out<<<dim3(16, 32), 256, 0, stream>>>(ybuf, Wot, (float*)d_out, 2048, 2048);
}

// Round 4
// 410.405 us; speedup vs baseline: 1.8089x; 1.8089x over previous
//
#include <hip/hip_runtime.h>
#include <hip/hip_bf16.h>

#define TT 2048
#define DM 2048
#define NH 16
#define KVH 4
#define HD 128

typedef __attribute__((ext_vector_type(8))) short bs8;
typedef __attribute__((ext_vector_type(4))) float fx4;
typedef __attribute__((ext_vector_type(4))) unsigned short us4;

__device__ inline unsigned short f2b(float f) {
  __hip_bfloat16 h = __float2bfloat16(f);
  return *reinterpret_cast<unsigned short*>(&h);
}

__device__ inline void gld_lds16(const ushort* g, ushort* l) {
  __builtin_amdgcn_global_load_lds(
      (const __attribute__((address_space(1))) void*)g,
      (__attribute__((address_space(3))) void*)l,
      16, 0, 0);
}

// ---------------- cast x: fp32 -> bf16, 4 elems/thread ----------------
__global__ __launch_bounds__(256) void cast_f32_bf16(const float* __restrict__ in,
                                                     ushort* __restrict__ out) {
  int i = blockIdx.x * 256 + threadIdx.x;
  float4 v = ((const float4*)in)[i];
  us4 o = {f2b(v.x), f2b(v.y), f2b(v.z), f2b(v.w)};
  ((us4*)out)[i] = o;
}

// ---------------- fused transpose+cast of all weights ----------------
// z=0: Wqkvt[3072][2048] from Wq|Wk|Wv   z=1: Wot[2048][2048] from Wo
__global__ __launch_bounds__(256) void transpose_cast_all(
    const float* __restrict__ Wq, const float* __restrict__ Wk,
    const float* __restrict__ Wv, const float* __restrict__ Wo,
    ushort* __restrict__ Wqkvt, ushort* __restrict__ Wot) {
  __shared__ float t[32][33];
  int tx = threadIdx.x, ty = threadIdx.y;  // block (32,8)
  int n0 = blockIdx.x * 32, k0 = blockIdx.y * 32;
  if (blockIdx.z == 0) {
    const float* src;
    int srcN, col0;
    if (n0 < 2048) { src = Wq; srcN = 2048; col0 = n0; }
    else if (n0 < 2560) { src = Wk; srcN = 512; col0 = n0 - 2048; }
    else { src = Wv; srcN = 512; col0 = n0 - 2560; }
    for (int jj = 0; jj < 4; ++jj)
      t[ty + jj * 8][tx] = src[(size_t)(k0 + ty + jj * 8) * srcN + col0 + tx];
    __syncthreads();
    for (int jj = 0; jj < 4; ++jj)
      Wqkvt[(size_t)(n0 + ty + jj * 8) * 2048 + k0 + tx] = f2b(t[tx][ty + jj * 8]);
  } else {
    if (n0 >= 2048) return;
    for (int jj = 0; jj < 4; ++jj)
      t[ty + jj * 8][tx] = Wo[(size_t)(k0 + ty + jj * 8) * 2048 + n0 + tx];
    __syncthreads();
    for (int jj = 0; jj < 4; ++jj)
      Wot[(size_t)(n0 + ty + jj * 8) * 2048 + k0 + tx] = f2b(t[tx][ty + jj * 8]);
  }
}

// ---------------- fused QKV GEMM: [4096 x 3072] = xb * Wqkvt^T ----------------
__global__ __launch_bounds__(256) void gemm_qkv(const ushort* __restrict__ A,
                                                const ushort* __restrict__ Bt,
                                                ushort* __restrict__ qo,
                                                ushort* __restrict__ ko,
                                                ushort* __restrict__ vo,
                                                int K) {
  __shared__ alignas(16) ushort As[128 * 64];
  __shared__ alignas(16) ushort Bs[128 * 64];
  const int tid = threadIdx.x;
  const int lane = tid & 63;
  const int wid = tid >> 6;
  const int wm = wid >> 1, wn = wid & 1;
  const int quad = lane >> 4, l16 = lane & 15;
  const int bm = blockIdx.y * 128, bn = blockIdx.x * 128;

  fx4 acc[4][4];
  for (int i = 0; i < 4; ++i)
    for (int j = 0; j < 4; ++j) acc[i][j] = (fx4){0.f, 0.f, 0.f, 0.f};

  const int r8 = lane >> 3, s8 = lane & 7;
  for (int k0 = 0; k0 < K; k0 += 64) {
    for (int i = 0; i < 4; ++i) {
      int m = i * 32 + wid * 8 + r8;
      int c = s8 ^ (m & 7);
      gld_lds16(A + (size_t)(bm + m) * K + k0 + c * 8, As + (i * 32 + wid * 8) * 64);
      gld_lds16(Bt + (size_t)(bn + m) * K + k0 + c * 8, Bs + (i * 32 + wid * 8) * 64);
    }
    __syncthreads();
    for (int ks = 0; ks < 2; ++ks) {
      bs8 af[4], bf[4];
      for (int mt = 0; mt < 4; ++mt) {
        int m = wm * 64 + mt * 16 + l16;
        int c = ks * 4 + quad;
        int slot = c ^ (m & 7);
        af[mt] = *(const bs8*)(As + m * 64 + slot * 8);
      }
      for (int nt = 0; nt < 4; ++nt) {
        int n = wn * 64 + nt * 16 + l16;
        int c = ks * 4 + quad;
        int slot = c ^ (n & 7);
        bf[nt] = *(const bs8*)(Bs + n * 64 + slot * 8);
      }
      for (int mt = 0; mt < 4; ++mt)
        for (int nt = 0; nt < 4; ++nt)
          acc[mt][nt] = __builtin_amdgcn_mfma_f32_16x16x32_bf16(af[mt], bf[nt],
                                                                acc[mt][nt], 0, 0, 0);
    }
    __syncthreads();
  }

  for (int mt = 0; mt < 4; ++mt)
    for (int nt = 0; nt < 4; ++nt)
      for (int r = 0; r < 4; ++r) {
        int row = bm + wm * 64 + mt * 16 + quad * 4 + r;
        int col = bn + wn * 64 + nt * 16 + l16;
        float v = acc[mt][nt][r];
        if (bn < 2048) {
          qo[(size_t)row * 2048 + col] = f2b(v);
        } else if (bn < 2560) {
          int kc = col - 2048;
          int b = row >> 11, t = row & 2047;
          int gg = kc >> 7, d = kc & 127;
          ko[((size_t)(b * KVH + gg) * TT + t) * HD + d] = f2b(v);
        } else {
          int vc = col - 2560;
          int b = row >> 11, t = row & 2047;
          int gg = vc >> 7, d = vc & 127;
          vo[((size_t)(b * KVH + gg) * HD + d) * TT + t] = f2b(v);
        }
      }
}

// ---------------- output-projection GEMM: fp32 out ----------------
__global__ __launch_bounds__(256) void gemm_out(const ushort* __restrict__ A,
                                                const ushort* __restrict__ Bt,
                                                float* __restrict__ Cout,
                                                int N, int K) {
  __shared__ alignas(16) ushort As[128 * 64];
  __shared__ alignas(16) ushort Bs[128 * 64];
  const int tid = threadIdx.x;
  const int lane = tid & 63;
  const int wid = tid >> 6;
  const int wm = wid >> 1, wn = wid & 1;
  const int quad = lane >> 4, l16 = lane & 15;
  const int bm = blockIdx.y * 128, bn = blockIdx.x * 128;

  fx4 acc[4][4];
  for (int i = 0; i < 4; ++i)
    for (int j = 0; j < 4; ++j) acc[i][j] = (fx4){0.f, 0.f, 0.f, 0.f};

  const int r8 = lane >> 3, s8 = lane & 7;
  for (int k0 = 0; k0 < K; k0 += 64) {
    for (int i = 0; i < 4; ++i) {
      int m = i * 32 + wid * 8 + r8;
      int c = s8 ^ (m & 7);
      gld_lds16(A + (size_t)(bm + m) * K + k0 + c * 8, As + (i * 32 + wid * 8) * 64);
      gld_lds16(Bt + (size_t)(bn + m) * K + k0 + c * 8, Bs + (i * 32 + wid * 8) * 64);
    }
    __syncthreads();
    for (int ks = 0; ks < 2; ++ks) {
      bs8 af[4], bf[4];
      for (int mt = 0; mt < 4; ++mt) {
        int m = wm * 64 + mt * 16 + l16;
        int c = ks * 4 + quad;
        int slot = c ^ (m & 7);
        af[mt] = *(const bs8*)(As + m * 64 + slot * 8);
      }
      for (int nt = 0; nt < 4; ++nt) {
        int n = wn * 64 + nt * 16 + l16;
        int c = ks * 4 + quad;
        int slot = c ^ (n & 7);
        bf[nt] = *(const bs8*)(Bs + n * 64 + slot * 8);
      }
      for (int mt = 0; mt < 4; ++mt)
        for (int nt = 0; nt < 4; ++nt)
          acc[mt][nt] = __builtin_amdgcn_mfma_f32_16x16x32_bf16(af[mt], bf[nt],
                                                                acc[mt][nt], 0, 0, 0);
    }
    __syncthreads();
  }

  for (int mt = 0; mt < 4; ++mt)
    for (int nt = 0; nt < 4; ++nt)
      for (int r = 0; r < 4; ++r) {
        int row = bm + wm * 64 + mt * 16 + quad * 4 + r;
        int col = bn + wn * 64 + nt * 16 + l16;
        Cout[(size_t)row * N + col] = acc[mt][nt][r];
      }
}

// ---------------- fused causal WGQA attention, pair-balanced ----------------
// grid = 512: bid -> (b, h, pair p). Block handles 64-q chunks cA=p and cB=31-p.
// nt loops are FULLY UNROLLED (compile-time nt) so s[]/o[] stay in registers;
// inactive-nt work is skipped via the uniform `actA` branch.
__global__ __launch_bounds__(256) void attn_kernel(const ushort* __restrict__ qb,
                                                   const ushort* __restrict__ kb,
                                                   const ushort* __restrict__ vt,
                                                   ushort* __restrict__ yb,
                                                   const float* __restrict__ wlog) {
  __shared__ alignas(16) ushort Ks[64 * 128];   // [key][d], chunk-swizzled
  __shared__ alignas(16) ushort Vs[128 * 64];   // [d][key], chunk-swizzled
  __shared__ alignas(16) ushort Ps[128 * 72];   // [q][key], stride 72 (pad)

  const int bid = blockIdx.x;
  const int p = bid & 15;
  const int h = (bid >> 4) & 15;
  const int b = bid >> 8;
  const int g = h >> 2;
  const int tid = threadIdx.x;
  const int lane = tid & 63;
  const int wid = tid >> 6;
  const int quad = lane >> 4;
  const int l16 = lane & 15;

  const int cA = p;        // short chunk: needs key-tiles 0..cA
  const int cB = 31 - p;   // long chunk:  needs key-tiles 0..cB
  const int qA = cA * 64 + wid * 16 + l16;
  const int qB = cB * 64 + wid * 16 + l16;

  const float scale = wlog[g] * 0.08838834764831845f;  // 1/sqrt(128)

  // Q fragments in registers (B-operand of S^T = K * Q^T); nt=0 -> cA, nt=1 -> cB
  bs8 qf[2][4];
#pragma unroll
  for (int nt = 0; nt < 2; ++nt) {
    int q = nt ? qB : qA;
    const ushort* qrow = qb + ((size_t)(b * TT + q)) * DM + h * HD;
#pragma unroll
    for (int ks = 0; ks < 4; ++ks)
      qf[nt][ks] = *(const bs8*)(qrow + ks * 32 + quad * 8);
  }

  float m_i[2] = {-INFINITY, -INFINITY};
  float l_i[2] = {0.f, 0.f};
  fx4 o[8][2];
#pragma unroll
  for (int i = 0; i < 8; ++i)
#pragma unroll
    for (int nt = 0; nt < 2; ++nt) o[i][nt] = (fx4){0.f, 0.f, 0.f, 0.f};

  const ushort* kbase = kb + (size_t)(b * KVH + g) * TT * HD;
  const ushort* vbase = vt + (size_t)(b * KVH + g) * HD * TT;

  for (int j = 0; j <= cB; ++j) {
    // ---- stage K tile (64 keys x 128 d) and V^T tile (128 d x 64 keys) ----
    {
      int r4 = lane >> 4, sidx = lane & 15;
#pragma unroll
      for (int i = 0; i < 4; ++i) {
        int key = i * 16 + wid * 4 + r4;
        int c = (sidx & 8) | ((sidx ^ key) & 7);
        gld_lds16(kbase + (size_t)(j * 64 + key) * HD + c * 8,
                  Ks + (i * 16 + wid * 4) * 128);
      }
      int r8 = lane >> 3, s8 = lane & 7;
#pragma unroll
      for (int i = 0; i < 4; ++i) {
        int d = i * 32 + wid * 8 + r8;
        int c = s8 ^ (d & 7);
        gld_lds16(vbase + (size_t)d * TT + j * 64 + c * 8,
                  Vs + (i * 32 + wid * 8) * 64);
      }
    }
    __syncthreads();

    const bool actA = (j <= cA);  // block-uniform: no divergence

    // ---- S^T = K * Q^T  (keys x queries), fp32 acc ----
    fx4 s[2][4];
#pragma unroll
    for (int nt = 0; nt < 2; ++nt)
#pragma unroll
      for (int mt = 0; mt < 4; ++mt) s[nt][mt] = (fx4){0.f, 0.f, 0.f, 0.f};
#pragma unroll
    for (int mt = 0; mt < 4; ++mt) {
      bs8 a[4];
      int key = mt * 16 + l16;
#pragma unroll
      for (int ks = 0; ks < 4; ++ks) {
        int c = ks * 4 + quad;
        int slot = (c & 8) | ((c ^ key) & 7);
        a[ks] = *(const bs8*)(Ks + key * 128 + slot * 8);
      }
#pragma unroll
      for (int ks = 0; ks < 4; ++ks)
        s[1][mt] = __builtin_amdgcn_mfma_f32_16x16x32_bf16(a[ks], qf[1][ks],
                                                           s[1][mt], 0, 0, 0);
      if (actA)
#pragma unroll
        for (int ks = 0; ks < 4; ++ks)
          s[0][mt] = __builtin_amdgcn_mfma_f32_16x16x32_bf16(a[ks], qf[0][ks],
                                                             s[0][mt], 0, 0, 0);
    }

    // ---- scale + mask + online softmax + P write (nt compile-time) ----
#pragma unroll
    for (int nt = 0; nt < 2; ++nt) {
      if (nt == 0 && !actA) continue;
      const int cq = nt ? cB : cA;
      const int q = nt ? qB : qA;
      const bool diag = (j == cq);
#pragma unroll
      for (int mt = 0; mt < 4; ++mt)
#pragma unroll
        for (int r = 0; r < 4; ++r) {
          float v = s[nt][mt][r] * scale;
          if (diag) {
            int key = j * 64 + mt * 16 + quad * 4 + r;
            if (key > q) v = -1e30f;
          }
          s[nt][mt][r] = v;
        }
      float mx = s[nt][0][0];
#pragma unroll
      for (int mt = 0; mt < 4; ++mt)
#pragma unroll
        for (int r = 0; r < 4; ++r) mx = fmaxf(mx, s[nt][mt][r]);
      mx = fmaxf(mx, __shfl_xor(mx, 16));
      mx = fmaxf(mx, __shfl_xor(mx, 32));
      float m_new = fmaxf(m_i[nt], mx);
      float alpha = __expf(m_i[nt] - m_new);
      float sum = 0.f;
#pragma unroll
      for (int mt = 0; mt < 4; ++mt)
#pragma unroll
        for (int r = 0; r < 4; ++r) {
          float pv = __expf(s[nt][mt][r] - m_new);
          s[nt][mt][r] = pv;
          sum += pv;
        }
      sum += __shfl_xor(sum, 16);
      sum += __shfl_xor(sum, 32);
      l_i[nt] = l_i[nt] * alpha + sum;
      m_i[nt] = m_new;
#pragma unroll
      for (int dmt = 0; dmt < 8; ++dmt)
#pragma unroll
        for (int r = 0; r < 4; ++r) o[dmt][nt][r] *= alpha;
      int qrow = wid * 32 + nt * 16 + l16;
#pragma unroll
      for (int mt = 0; mt < 4; ++mt) {
        us4 pw = {f2b(s[nt][mt][0]), f2b(s[nt][mt][1]),
                  f2b(s[nt][mt][2]), f2b(s[nt][mt][3])};
        *(us4*)(Ps + qrow * 72 + mt * 16 + quad * 4) = pw;
      }
    }

    // ---- O^T += V^T * P^T  (wave reads only its own P rows; no barrier) ----
#pragma unroll
    for (int ks = 0; ks < 2; ++ks) {
      bs8 va[8];
#pragma unroll
      for (int dmt = 0; dmt < 8; ++dmt) {
        int d = dmt * 16 + l16;
        int c = ks * 4 + quad;
        int slot = c ^ (d & 7);
        va[dmt] = *(const bs8*)(Vs + d * 64 + slot * 8);
      }
#pragma unroll
      for (int nt = 0; nt < 2; ++nt) {
        if (nt == 0 && !actA) continue;
        int qrow = wid * 32 + nt * 16 + l16;
        bs8 pb = *(const bs8*)(Ps + qrow * 72 + ks * 32 + quad * 8);
#pragma unroll
        for (int dmt = 0; dmt < 8; ++dmt)
          o[dmt][nt] = __builtin_amdgcn_mfma_f32_16x16x32_bf16(va[dmt], pb,
                                                               o[dmt][nt], 0, 0, 0);
      }
    }
    __syncthreads();
  }

  // ---- epilogue: normalize and write y (bf16, [b][t][h*128+d]) ----
#pragma unroll
  for (int nt = 0; nt < 2; ++nt) {
    float inv = 1.0f / l_i[nt];
    int q = nt ? qB : qA;
    ushort* yrow = yb + ((size_t)(b * TT + q)) * DM + h * HD;
#pragma unroll
    for (int dmt = 0; dmt < 8; ++dmt) {
      us4 w = {f2b(o[dmt][nt][0] * inv), f2b(o[dmt][nt][1] * inv),
               f2b(o[dmt][nt][2] * inv), f2b(o[dmt][nt][3] * inv)};
      *(us4*)(yrow + dmt * 16 + quad * 4) = w;
    }
  }
}

// ---------------- launch ----------------
extern "C" void kernel_launch(void* const* d_in, const int* in_sizes, int n_in,
                              void* d_out, int out_size, void* d_ws, size_t ws_size,
                              hipStream_t stream) {
  const float* x = (const float*)d_in[0];
  // d_in[1] = attn_mask: ignored (exact causal mask computed analytically)
  const float* Wq = (const float*)d_in[2];
  const float* Wk = (const float*)d_in[3];
  const float* Wv = (const float*)d_in[4];
  const float* Wo = (const float*)d_in[5];
  const float* wlog = (const float*)d_in[6];
  // d_in[7] = weight_values: unused by the reference

  char* ws = (char*)d_ws;
  ushort* xb = (ushort*)ws;     ws += (size_t)4096 * 2048 * 2;
  ushort* Wqkvt = (ushort*)ws;  ws += (size_t)3072 * 2048 * 2;
  ushort* Wot = (ushort*)ws;    ws += (size_t)2048 * 2048 * 2;
  ushort* qbuf = (ushort*)ws;   ws += (size_t)4096 * 2048 * 2;
  ushort* kbuf = (ushort*)ws;   ws += (size_t)2 * KVH * 2048 * 128 * 2;
  ushort* vbuf = (ushort*)ws;   ws += (size_t)2 * KVH * 2048 * 128 * 2;
  ushort* ybuf = (ushort*)ws;   ws += (size_t)4096 * 2048 * 2;

  cast_f32_bf16<<<8192, 256, 0, stream>>>(x, xb);
  transpose_cast_all<<<dim3(96, 64, 2), dim3(32, 8), 0, stream>>>(
      Wq, Wk, Wv, Wo, Wqkvt, Wot);
  gemm_qkv<<<dim3(24, 32), 256, 0, stream>>>(xb, Wqkvt, qbuf, kbuf, vbuf, 2048);
  attn_kernel<<<512, 256, 0, stream>>>(qbuf, kbuf, vbuf, ybuf, wlog);
  gemm_out<<<dim3(16, 32), 256, 0, stream>>>(ybuf, Wot, (float*)d_out, 2048, 2048);
}

// Round 5
// 359.364 us; speedup vs baseline: 2.0658x; 1.1420x over previous
//
#include <hip/hip_runtime.h>
#include <hip/hip_bf16.h>

#define TT 2048
#define DM 2048
#define NH 16
#define KVH 4
#define HD 128

typedef __attribute__((ext_vector_type(8))) short bs8;
typedef __attribute__((ext_vector_type(4))) float fx4;
typedef __attribute__((ext_vector_type(4))) unsigned short us4;

__device__ inline unsigned short f2b(float f) {
  __hip_bfloat16 h = __float2bfloat16(f);
  return *reinterpret_cast<unsigned short*>(&h);
}

__device__ inline void gld_lds16(const ushort* g, ushort* l) {
  __builtin_amdgcn_global_load_lds(
      (const __attribute__((address_space(1))) void*)g,
      (__attribute__((address_space(3))) void*)l,
      16, 0, 0);
}

// ---------------- cast x: fp32 -> bf16, 4 elems/thread ----------------
__global__ __launch_bounds__(256) void cast_f32_bf16(const float* __restrict__ in,
                                                     ushort* __restrict__ out) {
  int i = blockIdx.x * 256 + threadIdx.x;
  float4 v = ((const float4*)in)[i];
  us4 o = {f2b(v.x), f2b(v.y), f2b(v.z), f2b(v.w)};
  ((us4*)out)[i] = o;
}

// ---------------- fused transpose+cast of all weights ----------------
__global__ __launch_bounds__(256) void transpose_cast_all(
    const float* __restrict__ Wq, const float* __restrict__ Wk,
    const float* __restrict__ Wv, const float* __restrict__ Wo,
    ushort* __restrict__ Wqkvt, ushort* __restrict__ Wot) {
  __shared__ float t[32][33];
  int tx = threadIdx.x, ty = threadIdx.y;  // block (32,8)
  int n0 = blockIdx.x * 32, k0 = blockIdx.y * 32;
  if (blockIdx.z == 0) {
    const float* src;
    int srcN, col0;
    if (n0 < 2048) { src = Wq; srcN = 2048; col0 = n0; }
    else if (n0 < 2560) { src = Wk; srcN = 512; col0 = n0 - 2048; }
    else { src = Wv; srcN = 512; col0 = n0 - 2560; }
    for (int jj = 0; jj < 4; ++jj)
      t[ty + jj * 8][tx] = src[(size_t)(k0 + ty + jj * 8) * srcN + col0 + tx];
    __syncthreads();
    for (int jj = 0; jj < 4; ++jj)
      Wqkvt[(size_t)(n0 + ty + jj * 8) * 2048 + k0 + tx] = f2b(t[tx][ty + jj * 8]);
  } else {
    if (n0 >= 2048) return;
    for (int jj = 0; jj < 4; ++jj)
      t[ty + jj * 8][tx] = Wo[(size_t)(k0 + ty + jj * 8) * 2048 + n0 + tx];
    __syncthreads();
    for (int jj = 0; jj < 4; ++jj)
      Wot[(size_t)(n0 + ty + jj * 8) * 2048 + k0 + tx] = f2b(t[tx][ty + jj * 8]);
  }
}

// ---------------- fused QKV GEMM: [4096 x 3072] = xb * Wqkvt^T ----------------
__global__ __launch_bounds__(256) void gemm_qkv(const ushort* __restrict__ A,
                                                const ushort* __restrict__ Bt,
                                                ushort* __restrict__ qo,
                                                ushort* __restrict__ ko,
                                                ushort* __restrict__ vo,
                                                int K) {
  __shared__ alignas(16) ushort As[128 * 64];
  __shared__ alignas(16) ushort Bs[128 * 64];
  const int tid = threadIdx.x;
  const int lane = tid & 63;
  const int wid = tid >> 6;
  const int wm = wid >> 1, wn = wid & 1;
  const int quad = lane >> 4, l16 = lane & 15;
  const int bm = blockIdx.y * 128, bn = blockIdx.x * 128;

  fx4 acc[4][4];
  for (int i = 0; i < 4; ++i)
    for (int j = 0; j < 4; ++j) acc[i][j] = (fx4){0.f, 0.f, 0.f, 0.f};

  const int r8 = lane >> 3, s8 = lane & 7;
  for (int k0 = 0; k0 < K; k0 += 64) {
    for (int i = 0; i < 4; ++i) {
      int m = i * 32 + wid * 8 + r8;
      int c = s8 ^ (m & 7);
      gld_lds16(A + (size_t)(bm + m) * K + k0 + c * 8, As + (i * 32 + wid * 8) * 64);
      gld_lds16(Bt + (size_t)(bn + m) * K + k0 + c * 8, Bs + (i * 32 + wid * 8) * 64);
    }
    __syncthreads();
    for (int ks = 0; ks < 2; ++ks) {
      bs8 af[4], bf[4];
      for (int mt = 0; mt < 4; ++mt) {
        int m = wm * 64 + mt * 16 + l16;
        int c = ks * 4 + quad;
        int slot = c ^ (m & 7);
        af[mt] = *(const bs8*)(As + m * 64 + slot * 8);
      }
      for (int nt = 0; nt < 4; ++nt) {
        int n = wn * 64 + nt * 16 + l16;
        int c = ks * 4 + quad;
        int slot = c ^ (n & 7);
        bf[nt] = *(const bs8*)(Bs + n * 64 + slot * 8);
      }
      for (int mt = 0; mt < 4; ++mt)
        for (int nt = 0; nt < 4; ++nt)
          acc[mt][nt] = __builtin_amdgcn_mfma_f32_16x16x32_bf16(af[mt], bf[nt],
                                                                acc[mt][nt], 0, 0, 0);
    }
    __syncthreads();
  }

  for (int mt = 0; mt < 4; ++mt)
    for (int nt = 0; nt < 4; ++nt)
      for (int r = 0; r < 4; ++r) {
        int row = bm + wm * 64 + mt * 16 + quad * 4 + r;
        int col = bn + wn * 64 + nt * 16 + l16;
        float v = acc[mt][nt][r];
        if (bn < 2048) {
          qo[(size_t)row * 2048 + col] = f2b(v);
        } else if (bn < 2560) {
          int kc = col - 2048;
          int b = row >> 11, t = row & 2047;
          int gg = kc >> 7, d = kc & 127;
          ko[((size_t)(b * KVH + gg) * TT + t) * HD + d] = f2b(v);
        } else {
          int vc = col - 2560;
          int b = row >> 11, t = row & 2047;
          int gg = vc >> 7, d = vc & 127;
          vo[((size_t)(b * KVH + gg) * HD + d) * TT + t] = f2b(v);
        }
      }
}

// ---------------- output-projection GEMM: fp32 out ----------------
__global__ __launch_bounds__(256) void gemm_out(const ushort* __restrict__ A,
                                                const ushort* __restrict__ Bt,
                                                float* __restrict__ Cout,
                                                int N, int K) {
  __shared__ alignas(16) ushort As[128 * 64];
  __shared__ alignas(16) ushort Bs[128 * 64];
  const int tid = threadIdx.x;
  const int lane = tid & 63;
  const int wid = tid >> 6;
  const int wm = wid >> 1, wn = wid & 1;
  const int quad = lane >> 4, l16 = lane & 15;
  const int bm = blockIdx.y * 128, bn = blockIdx.x * 128;

  fx4 acc[4][4];
  for (int i = 0; i < 4; ++i)
    for (int j = 0; j < 4; ++j) acc[i][j] = (fx4){0.f, 0.f, 0.f, 0.f};

  const int r8 = lane >> 3, s8 = lane & 7;
  for (int k0 = 0; k0 < K; k0 += 64) {
    for (int i = 0; i < 4; ++i) {
      int m = i * 32 + wid * 8 + r8;
      int c = s8 ^ (m & 7);
      gld_lds16(A + (size_t)(bm + m) * K + k0 + c * 8, As + (i * 32 + wid * 8) * 64);
      gld_lds16(Bt + (size_t)(bn + m) * K + k0 + c * 8, Bs + (i * 32 + wid * 8) * 64);
    }
    __syncthreads();
    for (int ks = 0; ks < 2; ++ks) {
      bs8 af[4], bf[4];
      for (int mt = 0; mt < 4; ++mt) {
        int m = wm * 64 + mt * 16 + l16;
        int c = ks * 4 + quad;
        int slot = c ^ (m & 7);
        af[mt] = *(const bs8*)(As + m * 64 + slot * 8);
      }
      for (int nt = 0; nt < 4; ++nt) {
        int n = wn * 64 + nt * 16 + l16;
        int c = ks * 4 + quad;
        int slot = c ^ (n & 7);
        bf[nt] = *(const bs8*)(Bs + n * 64 + slot * 8);
      }
      for (int mt = 0; mt < 4; ++mt)
        for (int nt = 0; nt < 4; ++nt)
          acc[mt][nt] = __builtin_amdgcn_mfma_f32_16x16x32_bf16(af[mt], bf[nt],
                                                                acc[mt][nt], 0, 0, 0);
    }
    __syncthreads();
  }

  for (int mt = 0; mt < 4; ++mt)
    for (int nt = 0; nt < 4; ++nt)
      for (int r = 0; r < 4; ++r) {
        int row = bm + wm * 64 + mt * 16 + quad * 4 + r;
        int col = bn + wn * 64 + nt * 16 + l16;
        Cout[(size_t)row * N + col] = acc[mt][nt][r];
      }
}

// ---------------- fused causal WGQA attention ----------------
// 512 blocks, each a 128-query chunk with minimal iterations (2qt+2).
// Complementary qt mapping: co-resident blocks bid and bid+256 get qt and
// 15-qt -> every CU hosts exactly 34 iterations total (balanced), and the
// two independent blocks hide each other's staging latency.
__global__ __launch_bounds__(256) void attn_kernel(const ushort* __restrict__ qb,
                                                   const ushort* __restrict__ kb,
                                                   const ushort* __restrict__ vt,
                                                   ushort* __restrict__ yb,
                                                   const float* __restrict__ wlog) {
  __shared__ alignas(16) ushort Ks[64 * 128];   // [key][d], chunk-swizzled
  __shared__ alignas(16) ushort Vs[128 * 64];   // [d][key], chunk-swizzled
  __shared__ alignas(16) ushort Ps[128 * 72];   // [q][key], stride 72 (pad)

  const int bid = blockIdx.x;
  const int qt = (bid & 256) ? (bid & 15) : 15 - (bid & 15);
  const int h = (bid >> 4) & 15;
  const int b = bid >> 8;
  const int g = h >> 2;
  const int tid = threadIdx.x;
  const int lane = tid & 63;
  const int wid = tid >> 6;
  const int quad = lane >> 4;
  const int l16 = lane & 15;
  const int qw = qt * 128 + wid * 32;

  const float scale = wlog[g] * 0.08838834764831845f;  // 1/sqrt(128)

  // Q fragments in registers (B-operand of S^T = K * Q^T)
  bs8 qf[2][4];
#pragma unroll
  for (int nt = 0; nt < 2; ++nt) {
    int q = qw + nt * 16 + l16;
    const ushort* qrow = qb + ((size_t)(b * TT + q)) * DM + h * HD;
#pragma unroll
    for (int ks = 0; ks < 4; ++ks)
      qf[nt][ks] = *(const bs8*)(qrow + ks * 32 + quad * 8);
  }

  float m_i[2] = {-INFINITY, -INFINITY};  // running max of RAW logits
  float l_i[2] = {0.f, 0.f};
  fx4 o[8][2];
#pragma unroll
  for (int i = 0; i < 8; ++i)
#pragma unroll
    for (int nt = 0; nt < 2; ++nt) o[i][nt] = (fx4){0.f, 0.f, 0.f, 0.f};

  const ushort* kbase = kb + (size_t)(b * KVH + g) * TT * HD;
  const ushort* vbase = vt + (size_t)(b * KVH + g) * HD * TT;

  // persistent staging pointers (incremented by constant strides each iter)
  const ushort* kp[4];
  const ushort* vp[4];
  {
    int r4i = lane >> 4, sidx = lane & 15;
#pragma unroll
    for (int i = 0; i < 4; ++i) {
      int key = i * 16 + wid * 4 + r4i;
      int c = (sidx & 8) | ((sidx ^ key) & 7);
      kp[i] = kbase + (size_t)key * HD + c * 8;
    }
    int r8 = lane >> 3, s8 = lane & 7;
#pragma unroll
    for (int i = 0; i < 4; ++i) {
      int d = i * 32 + wid * 8 + r8;
      int c = s8 ^ (d & 7);
      vp[i] = vbase + (size_t)d * TT + c * 8;
    }
  }

  const int jmax = 2 * qt + 1;
  for (int j = 0; j <= jmax; ++j) {
    // ---- stage K tile (64 keys x 128 d) and V^T tile (128 d x 64 keys) ----
#pragma unroll
    for (int i = 0; i < 4; ++i) {
      gld_lds16(kp[i], Ks + (i * 16 + wid * 4) * 128);
      kp[i] += 64 * HD;
      gld_lds16(vp[i], Vs + (i * 32 + wid * 8) * 64);
      vp[i] += 64;
    }
    __syncthreads();

    if (j * 64 <= qw + 31) {  // wave has at least one unmasked key
      // ---- S^T = K * Q^T  (keys x queries), fp32 acc ----
      fx4 s[2][4];
#pragma unroll
      for (int nt = 0; nt < 2; ++nt)
#pragma unroll
        for (int mt = 0; mt < 4; ++mt) s[nt][mt] = (fx4){0.f, 0.f, 0.f, 0.f};
#pragma unroll
      for (int mt = 0; mt < 4; ++mt) {
        bs8 a[4];
        int key = mt * 16 + l16;
#pragma unroll
        for (int ks = 0; ks < 4; ++ks) {
          int c = ks * 4 + quad;
          int slot = (c & 8) | ((c ^ key) & 7);
          a[ks] = *(const bs8*)(Ks + key * 128 + slot * 8);
        }
#pragma unroll
        for (int nt = 0; nt < 2; ++nt)
#pragma unroll
          for (int ks = 0; ks < 4; ++ks)
            s[nt][mt] = __builtin_amdgcn_mfma_f32_16x16x32_bf16(a[ks], qf[nt][ks],
                                                                s[nt][mt], 0, 0, 0);
      }

      const bool diag = (j >= 2 * qt);

      // ---- online softmax on RAW logits (scale folded into fma+exp) ----
#pragma unroll
      for (int nt = 0; nt < 2; ++nt) {
        const int q = qw + nt * 16 + l16;
        if (diag) {
#pragma unroll
          for (int mt = 0; mt < 4; ++mt)
#pragma unroll
            for (int r = 0; r < 4; ++r) {
              int key = j * 64 + mt * 16 + quad * 4 + r;
              if (key > q) s[nt][mt][r] = -1e30f;
            }
        }
        float mx = s[nt][0][0];
#pragma unroll
        for (int mt = 0; mt < 4; ++mt)
#pragma unroll
          for (int r = 0; r < 4; ++r) mx = fmaxf(mx, s[nt][mt][r]);
        mx = fmaxf(mx, __shfl_xor(mx, 16));
        mx = fmaxf(mx, __shfl_xor(mx, 32));
        float m_new = fmaxf(m_i[nt], mx);
        float alpha = __expf((m_i[nt] - m_new) * scale);
        float negb = -m_new * scale;
        float sum = 0.f;
#pragma unroll
        for (int mt = 0; mt < 4; ++mt)
#pragma unroll
          for (int r = 0; r < 4; ++r) {
            float pv = __expf(fmaf(s[nt][mt][r], scale, negb));
            s[nt][mt][r] = pv;
            sum += pv;
          }
        sum += __shfl_xor(sum, 16);
        sum += __shfl_xor(sum, 32);
        l_i[nt] = l_i[nt] * alpha + sum;
        m_i[nt] = m_new;
#pragma unroll
        for (int dmt = 0; dmt < 8; ++dmt)
#pragma unroll
          for (int r = 0; r < 4; ++r) o[dmt][nt][r] *= alpha;
        int qrow = wid * 32 + nt * 16 + l16;
#pragma unroll
        for (int mt = 0; mt < 4; ++mt) {
          us4 pw = {f2b(s[nt][mt][0]), f2b(s[nt][mt][1]),
                    f2b(s[nt][mt][2]), f2b(s[nt][mt][3])};
          *(us4*)(Ps + qrow * 72 + mt * 16 + quad * 4) = pw;
        }
      }

      // ---- O^T += V^T * P^T  (wave reads only its own P rows; no barrier) ----
#pragma unroll
      for (int ks = 0; ks < 2; ++ks) {
        bs8 va[8];
#pragma unroll
        for (int dmt = 0; dmt < 8; ++dmt) {
          int d = dmt * 16 + l16;
          int c = ks * 4 + quad;
          int slot = c ^ (d & 7);
          va[dmt] = *(const bs8*)(Vs + d * 64 + slot * 8);
        }
#pragma unroll
        for (int nt = 0; nt < 2; ++nt) {
          int qrow = wid * 32 + nt * 16 + l16;
          bs8 pb = *(const bs8*)(Ps + qrow * 72 + ks * 32 + quad * 8);
#pragma unroll
          for (int dmt = 0; dmt < 8; ++dmt)
            o[dmt][nt] = __builtin_amdgcn_mfma_f32_16x16x32_bf16(va[dmt], pb,
                                                                 o[dmt][nt], 0, 0, 0);
        }
      }
    }
    __syncthreads();
  }

  // ---- epilogue: normalize and write y (bf16, [b][t][h*128+d]) ----
#pragma unroll
  for (int nt = 0; nt < 2; ++nt) {
    float inv = 1.0f / l_i[nt];
    int q = qw + nt * 16 + l16;
    ushort* yrow = yb + ((size_t)(b * TT + q)) * DM + h * HD;
#pragma unroll
    for (int dmt = 0; dmt < 8; ++dmt) {
      us4 w = {f2b(o[dmt][nt][0] * inv), f2b(o[dmt][nt][1] * inv),
               f2b(o[dmt][nt][2] * inv), f2b(o[dmt][nt][3] * inv)};
      *(us4*)(yrow + dmt * 16 + quad * 4) = w;
    }
  }
}

// ---------------- launch ----------------
extern "C" void kernel_launch(void* const* d_in, const int* in_sizes, int n_in,
                              void* d_out, int out_size, void* d_ws, size_t ws_size,
                              hipStream_t stream) {
  const float* x = (const float*)d_in[0];
  // d_in[1] = attn_mask: ignored (exact causal mask computed analytically)
  const float* Wq = (const float*)d_in[2];
  const float* Wk = (const float*)d_in[3];
  const float* Wv = (const float*)d_in[4];
  const float* Wo = (const float*)d_in[5];
  const float* wlog = (const float*)d_in[6];
  // d_in[7] = weight_values: unused by the reference

  char* ws = (char*)d_ws;
  ushort* xb = (ushort*)ws;     ws += (size_t)4096 * 2048 * 2;
  ushort* Wqkvt = (ushort*)ws;  ws += (size_t)3072 * 2048 * 2;
  ushort* Wot = (ushort*)ws;    ws += (size_t)2048 * 2048 * 2;
  ushort* qbuf = (ushort*)ws;   ws += (size_t)4096 * 2048 * 2;
  ushort* kbuf = (ushort*)ws;   ws += (size_t)2 * KVH * 2048 * 128 * 2;
  ushort* vbuf = (ushort*)ws;   ws += (size_t)2 * KVH * 2048 * 128 * 2;
  ushort* ybuf = (ushort*)ws;   ws += (size_t)4096 * 2048 * 2;

  cast_f32_bf16<<<8192, 256, 0, stream>>>(x, xb);
  transpose_cast_all<<<dim3(96, 64, 2), dim3(32, 8), 0, stream>>>(
      Wq, Wk, Wv, Wo, Wqkvt, Wot);
  gemm_qkv<<<dim3(24, 32), 256, 0, stream>>>(xb, Wqkvt, qbuf, kbuf, vbuf, 2048);
  attn_kernel<<<512, 256, 0, stream>>>(qbuf, kbuf, vbuf, ybuf, wlog);
  gemm_out<<<dim3(16, 32), 256, 0, stream>>>(ybuf, Wot, (float*)d_out, 2048, 2048);
}

// Round 7
// 313.882 us; speedup vs baseline: 2.3652x; 1.1449x over previous
//
#include <hip/hip_runtime.h>
#include <hip/hip_bf16.h>

#define TT 2048
#define DM 2048
#define NH 16
#define KVH 4
#define HD 128

typedef __attribute__((ext_vector_type(8))) short bs8;
typedef __attribute__((ext_vector_type(4))) float fx4;
typedef __attribute__((ext_vector_type(4))) unsigned short us4;

__device__ inline unsigned short f2b(float f) {
  __hip_bfloat16 h = __float2bfloat16(f);
  return *reinterpret_cast<unsigned short*>(&h);
}

__device__ inline void gld_lds16(const ushort* g, ushort* l) {
  __builtin_amdgcn_global_load_lds(
      (const __attribute__((address_space(1))) void*)g,
      (__attribute__((address_space(3))) void*)l,
      16, 0, 0);
}

// ---------------- cast x: fp32 -> bf16, 4 elems/thread ----------------
__global__ __launch_bounds__(256) void cast_f32_bf16(const float* __restrict__ in,
                                                     ushort* __restrict__ out) {
  int i = blockIdx.x * 256 + threadIdx.x;
  float4 v = ((const float4*)in)[i];
  us4 o = {f2b(v.x), f2b(v.y), f2b(v.z), f2b(v.w)};
  ((us4*)out)[i] = o;
}

// ---------------- fused transpose+cast of all weights ----------------
__global__ __launch_bounds__(256) void transpose_cast_all(
    const float* __restrict__ Wq, const float* __restrict__ Wk,
    const float* __restrict__ Wv, const float* __restrict__ Wo,
    ushort* __restrict__ Wqkvt, ushort* __restrict__ Wot) {
  __shared__ float t[32][33];
  int tx = threadIdx.x, ty = threadIdx.y;  // block (32,8)
  int n0 = blockIdx.x * 32, k0 = blockIdx.y * 32;
  if (blockIdx.z == 0) {
    const float* src;
    int srcN, col0;
    if (n0 < 2048) { src = Wq; srcN = 2048; col0 = n0; }
    else if (n0 < 2560) { src = Wk; srcN = 512; col0 = n0 - 2048; }
    else { src = Wv; srcN = 512; col0 = n0 - 2560; }
    for (int jj = 0; jj < 4; ++jj)
      t[ty + jj * 8][tx] = src[(size_t)(k0 + ty + jj * 8) * srcN + col0 + tx];
    __syncthreads();
    for (int jj = 0; jj < 4; ++jj)
      Wqkvt[(size_t)(n0 + ty + jj * 8) * 2048 + k0 + tx] = f2b(t[tx][ty + jj * 8]);
  } else {
    if (n0 >= 2048) return;
    for (int jj = 0; jj < 4; ++jj)
      t[ty + jj * 8][tx] = Wo[(size_t)(k0 + ty + jj * 8) * 2048 + n0 + tx];
    __syncthreads();
    for (int jj = 0; jj < 4; ++jj)
      Wot[(size_t)(n0 + ty + jj * 8) * 2048 + k0 + tx] = f2b(t[tx][ty + jj * 8]);
  }
}

// ---------------- fused QKV GEMM: [4096 x 3072] = xb * Wqkvt^T ----------------
__global__ __launch_bounds__(256) void gemm_qkv(const ushort* __restrict__ A,
                                                const ushort* __restrict__ Bt,
                                                ushort* __restrict__ qo,
                                                ushort* __restrict__ ko,
                                                ushort* __restrict__ vo,
                                                int K) {
  __shared__ alignas(16) ushort As[128 * 64];
  __shared__ alignas(16) ushort Bs[128 * 64];
  const int tid = threadIdx.x;
  const int lane = tid & 63;
  const int wid = tid >> 6;
  const int wm = wid >> 1, wn = wid & 1;
  const int quad = lane >> 4, l16 = lane & 15;
  const int bm = blockIdx.y * 128, bn = blockIdx.x * 128;

  fx4 acc[4][4];
  for (int i = 0; i < 4; ++i)
    for (int j = 0; j < 4; ++j) acc[i][j] = (fx4){0.f, 0.f, 0.f, 0.f};

  const int r8 = lane >> 3, s8 = lane & 7;
  for (int k0 = 0; k0 < K; k0 += 64) {
    for (int i = 0; i < 4; ++i) {
      int m = i * 32 + wid * 8 + r8;
      int c = s8 ^ (m & 7);
      gld_lds16(A + (size_t)(bm + m) * K + k0 + c * 8, As + (i * 32 + wid * 8) * 64);
      gld_lds16(Bt + (size_t)(bn + m) * K + k0 + c * 8, Bs + (i * 32 + wid * 8) * 64);
    }
    __syncthreads();
    for (int ks = 0; ks < 2; ++ks) {
      bs8 af[4], bf[4];
      for (int mt = 0; mt < 4; ++mt) {
        int m = wm * 64 + mt * 16 + l16;
        int c = ks * 4 + quad;
        int slot = c ^ (m & 7);
        af[mt] = *(const bs8*)(As + m * 64 + slot * 8);
      }
      for (int nt = 0; nt < 4; ++nt) {
        int n = wn * 64 + nt * 16 + l16;
        int c = ks * 4 + quad;
        int slot = c ^ (n & 7);
        bf[nt] = *(const bs8*)(Bs + n * 64 + slot * 8);
      }
      for (int mt = 0; mt < 4; ++mt)
        for (int nt = 0; nt < 4; ++nt)
          acc[mt][nt] = __builtin_amdgcn_mfma_f32_16x16x32_bf16(af[mt], bf[nt],
                                                                acc[mt][nt], 0, 0, 0);
    }
    __syncthreads();
  }

  for (int mt = 0; mt < 4; ++mt)
    for (int nt = 0; nt < 4; ++nt)
      for (int r = 0; r < 4; ++r) {
        int row = bm + wm * 64 + mt * 16 + quad * 4 + r;
        int col = bn + wn * 64 + nt * 16 + l16;
        float v = acc[mt][nt][r];
        if (bn < 2048) {
          qo[(size_t)row * 2048 + col] = f2b(v);
        } else if (bn < 2560) {
          int kc = col - 2048;
          int b = row >> 11, t = row & 2047;
          int gg = kc >> 7, d = kc & 127;
          ko[((size_t)(b * KVH + gg) * TT + t) * HD + d] = f2b(v);
        } else {
          int vc = col - 2560;
          int b = row >> 11, t = row & 2047;
          int gg = vc >> 7, d = vc & 127;
          vo[((size_t)(b * KVH + gg) * HD + d) * TT + t] = f2b(v);
        }
      }
}

// ---------------- output-projection GEMM: fp32 out ----------------
__global__ __launch_bounds__(256) void gemm_out(const ushort* __restrict__ A,
                                                const ushort* __restrict__ Bt,
                                                float* __restrict__ Cout,
                                                int N, int K) {
  __shared__ alignas(16) ushort As[128 * 64];
  __shared__ alignas(16) ushort Bs[128 * 64];
  const int tid = threadIdx.x;
  const int lane = tid & 63;
  const int wid = tid >> 6;
  const int wm = wid >> 1, wn = wid & 1;
  const int quad = lane >> 4, l16 = lane & 15;
  const int bm = blockIdx.y * 128, bn = blockIdx.x * 128;

  fx4 acc[4][4];
  for (int i = 0; i < 4; ++i)
    for (int j = 0; j < 4; ++j) acc[i][j] = (fx4){0.f, 0.f, 0.f, 0.f};

  const int r8 = lane >> 3, s8 = lane & 7;
  for (int k0 = 0; k0 < K; k0 += 64) {
    for (int i = 0; i < 4; ++i) {
      int m = i * 32 + wid * 8 + r8;
      int c = s8 ^ (m & 7);
      gld_lds16(A + (size_t)(bm + m) * K + k0 + c * 8, As + (i * 32 + wid * 8) * 64);
      gld_lds16(Bt + (size_t)(bn + m) * K + k0 + c * 8, Bs + (i * 32 + wid * 8) * 64);
    }
    __syncthreads();
    for (int ks = 0; ks < 2; ++ks) {
      bs8 af[4], bf[4];
      for (int mt = 0; mt < 4; ++mt) {
        int m = wm * 64 + mt * 16 + l16;
        int c = ks * 4 + quad;
        int slot = c ^ (m & 7);
        af[mt] = *(const bs8*)(As + m * 64 + slot * 8);
      }
      for (int nt = 0; nt < 4; ++nt) {
        int n = wn * 64 + nt * 16 + l16;
        int c = ks * 4 + quad;
        int slot = c ^ (n & 7);
        bf[nt] = *(const bs8*)(Bs + n * 64 + slot * 8);
      }
      for (int mt = 0; mt < 4; ++mt)
        for (int nt = 0; nt < 4; ++nt)
          acc[mt][nt] = __builtin_amdgcn_mfma_f32_16x16x32_bf16(af[mt], bf[nt],
                                                                acc[mt][nt], 0, 0, 0);
    }
    __syncthreads();
  }

  for (int mt = 0; mt < 4; ++mt)
    for (int nt = 0; nt < 4; ++nt)
      for (int r = 0; r < 4; ++r) {
        int row = bm + wm * 64 + mt * 16 + quad * 4 + r;
        int col = bn + wn * 64 + nt * 16 + l16;
        Cout[(size_t)row * N + col] = acc[mt][nt][r];
      }
}

// ---------------- fused causal WGQA attention, 8-wave blocks ----------------
// 512 blocks x 512 threads. Block = 128-query chunk; wave owns 16 queries.
// Complementary qt mapping keeps per-CU iteration count uniform (34) and the
// two co-resident blocks hide each other's staging latency. 16 waves/CU.
__global__ __launch_bounds__(512, 4) void attn_kernel(const ushort* __restrict__ qb,
                                                      const ushort* __restrict__ kb,
                                                      const ushort* __restrict__ vt,
                                                      ushort* __restrict__ yb,
                                                      const float* __restrict__ wlog) {
  __shared__ alignas(16) ushort Ks[64 * 128];   // [key][d], chunk-swizzled
  __shared__ alignas(16) ushort Vs[128 * 64];   // [d][key], chunk-swizzled
  __shared__ alignas(16) ushort Ps[128 * 72];   // [q][key], stride 72 (pad)

  const int bid = blockIdx.x;
  const int qt = (bid & 256) ? (bid & 15) : 15 - (bid & 15);
  const int h = (bid >> 4) & 15;
  const int b = bid >> 8;
  const int g = h >> 2;
  const int tid = threadIdx.x;
  const int lane = tid & 63;
  const int wid = tid >> 6;        // 0..7
  const int quad = lane >> 4;
  const int l16 = lane & 15;
  const int qw = qt * 128 + wid * 16;   // wave's first query

  const float scale = wlog[g] * 0.08838834764831845f;  // 1/sqrt(128)

  // Q fragments in registers (B-operand of S^T = K * Q^T)
  bs8 qf[4];
  {
    int q = qw + l16;
    const ushort* qrow = qb + ((size_t)(b * TT + q)) * DM + h * HD;
#pragma unroll
    for (int ks = 0; ks < 4; ++ks)
      qf[ks] = *(const bs8*)(qrow + ks * 32 + quad * 8);
  }

  float m_i = -INFINITY;  // running max of RAW logits
  float l_i = 0.f;
  fx4 o[8];
#pragma unroll
  for (int i = 0; i < 8; ++i) o[i] = (fx4){0.f, 0.f, 0.f, 0.f};

  const ushort* kbase = kb + (size_t)(b * KVH + g) * TT * HD;
  const ushort* vbase = vt + (size_t)(b * KVH + g) * HD * TT;

  // persistent staging pointers; each thread stages 2 K-slots + 2 V-slots
  const ushort* kp;
  const ushort* vp;
  {
    int keyr = wid * 4 + (lane >> 4);          // 0..31
    int si = lane & 15;
    int ck = (si & 8) | ((si ^ keyr) & 7);
    kp = kbase + (size_t)keyr * HD + ck * 8;
    int dr = wid * 8 + (lane >> 3);            // 0..63
    int s8 = lane & 7;
    int cv = s8 ^ (dr & 7);
    vp = vbase + (size_t)dr * TT + cv * 8;
  }

  const int jmax = 2 * qt + 1;
  for (int j = 0; j <= jmax; ++j) {
    // ---- stage K tile (64x128) and V^T tile (128x64): 4 lds-DMAs/thread ----
    gld_lds16(kp, Ks + wid * 512);               // K rows wid*4   .. +3
    gld_lds16(kp + 32 * HD, Ks + 4096 + wid * 512);  // K rows 32+wid*4
    gld_lds16(vp, Vs + wid * 512);               // V rows wid*8   .. +7
    gld_lds16(vp + 64 * TT, Vs + 4096 + wid * 512);  // V rows 64+wid*8
    kp += 64 * HD;
    vp += 64;
    __syncthreads();

    if (j * 64 <= qw + 15) {  // wave has at least one unmasked key
      // ---- S^T = K * Q^T  (64 keys x 16 queries), fp32 acc ----
      fx4 s[4];
#pragma unroll
      for (int mt = 0; mt < 4; ++mt) s[mt] = (fx4){0.f, 0.f, 0.f, 0.f};
#pragma unroll
      for (int mt = 0; mt < 4; ++mt) {
        bs8 a[4];
        int key = mt * 16 + l16;
#pragma unroll
        for (int ks = 0; ks < 4; ++ks) {
          int c = ks * 4 + quad;
          int slot = (c & 8) | ((c ^ key) & 7);
          a[ks] = *(const bs8*)(Ks + key * 128 + slot * 8);
        }
#pragma unroll
        for (int ks = 0; ks < 4; ++ks)
          s[mt] = __builtin_amdgcn_mfma_f32_16x16x32_bf16(a[ks], qf[ks],
                                                          s[mt], 0, 0, 0);
      }

      // ---- causal mask: needed iff tile max key > wave min query ----
      const int q = qw + l16;
      if (j * 64 + 63 > qw) {
#pragma unroll
        for (int mt = 0; mt < 4; ++mt)
#pragma unroll
          for (int r = 0; r < 4; ++r) {
            int key = j * 64 + mt * 16 + quad * 4 + r;
            if (key > q) s[mt][r] = -1e30f;
          }
      }
      float mx = s[0][0];
#pragma unroll
      for (int mt = 0; mt < 4; ++mt)
#pragma unroll
        for (int r = 0; r < 4; ++r) mx = fmaxf(mx, s[mt][r]);
      mx = fmaxf(mx, __shfl_xor(mx, 16));
      mx = fmaxf(mx, __shfl_xor(mx, 32));
      float m_new = fmaxf(m_i, mx);
      float alpha = __expf((m_i - m_new) * scale);
      float negb = -m_new * scale;
      float sum = 0.f;
#pragma unroll
      for (int mt = 0; mt < 4; ++mt)
#pragma unroll
        for (int r = 0; r < 4; ++r) {
          float pv = __expf(fmaf(s[mt][r], scale, negb));
          s[mt][r] = pv;
          sum += pv;
        }
      sum += __shfl_xor(sum, 16);
      sum += __shfl_xor(sum, 32);
      l_i = l_i * alpha + sum;
      m_i = m_new;
#pragma unroll
      for (int dmt = 0; dmt < 8; ++dmt)
#pragma unroll
        for (int r = 0; r < 4; ++r) o[dmt][r] *= alpha;

      // P (bf16) to LDS in [q][key] layout; wave touches only its 16 rows
      int qrow = wid * 16 + l16;
#pragma unroll
      for (int mt = 0; mt < 4; ++mt) {
        us4 pw = {f2b(s[mt][0]), f2b(s[mt][1]), f2b(s[mt][2]), f2b(s[mt][3])};
        *(us4*)(Ps + qrow * 72 + mt * 16 + quad * 4) = pw;
      }

      // ---- O^T += V^T * P^T  (no barrier: wave reads only its own P rows) ----
#pragma unroll
      for (int ks = 0; ks < 2; ++ks) {
        bs8 pb = *(const bs8*)(Ps + qrow * 72 + ks * 32 + quad * 8);
#pragma unroll
        for (int dmt = 0; dmt < 8; ++dmt) {
          int d = dmt * 16 + l16;
          int c = ks * 4 + quad;
          int slot = c ^ (d & 7);
          bs8 va = *(const bs8*)(Vs + d * 64 + slot * 8);
          o[dmt] = __builtin_amdgcn_mfma_f32_16x16x32_bf16(va, pb, o[dmt], 0, 0, 0);
        }
      }
    }
    __syncthreads();
  }

  // ---- epilogue: normalize and write y (bf16, [b][t][h*128+d]) ----
  {
    float inv = 1.0f / l_i;
    int q = qw + l16;
    ushort* yrow = yb + ((size_t)(b * TT + q)) * DM + h * HD;
#pragma unroll
    for (int dmt = 0; dmt < 8; ++dmt) {
      us4 w = {f2b(o[dmt][0] * inv), f2b(o[dmt][1] * inv),
               f2b(o[dmt][2] * inv), f2b(o[dmt][3] * inv)};
      *(us4*)(yrow + dmt * 16 + quad * 4) = w;
    }
  }
}

// ---------------- launch ----------------
extern "C" void kernel_launch(void* const* d_in, const int* in_sizes, int n_in,
                              void* d_out, int out_size, void* d_ws, size_t ws_size,
                              hipStream_t stream) {
  const float* x = (const float*)d_in[0];
  // d_in[1] = attn_mask: ignored (exact causal mask computed analytically)
  const float* Wq = (const float*)d_in[2];
  const float* Wk = (const float*)d_in[3];
  const float* Wv = (const float*)d_in[4];
  const float* Wo = (const float*)d_in[5];
  const float* wlog = (const float*)d_in[6];
  // d_in[7] = weight_values: unused by the reference

  char* ws = (char*)d_ws;
  ushort* xb = (ushort*)ws;     ws += (size_t)4096 * 2048 * 2;
  ushort* Wqkvt = (ushort*)ws;  ws += (size_t)3072 * 2048 * 2;
  ushort* Wot = (ushort*)ws;    ws += (size_t)2048 * 2048 * 2;
  ushort* qbuf = (ushort*)ws;   ws += (size_t)4096 * 2048 * 2;
  ushort* kbuf = (ushort*)ws;   ws += (size_t)2 * KVH * 2048 * 128 * 2;
  ushort* vbuf = (ushort*)ws;   ws += (size_t)2 * KVH * 2048 * 128 * 2;
  ushort* ybuf = (ushort*)ws;   ws += (size_t)4096 * 2048 * 2;

  cast_f32_bf16<<<8192, 256, 0, stream>>>(x, xb);
  transpose_cast_all<<<dim3(96, 64, 2), dim3(32, 8), 0, stream>>>(
      Wq, Wk, Wv, Wo, Wqkvt, Wot);
  gemm_qkv<<<dim3(24, 32), 256, 0, stream>>>(xb, Wqkvt, qbuf, kbuf, vbuf, 2048);
  attn_kernel<<<512, 512, 0, stream>>>(qbuf, kbuf, vbuf, ybuf, wlog);
  gemm_out<<<dim3(16, 32), 256, 0, stream>>>(ybuf, Wot, (float*)d_out, 2048, 2048);
}

// Round 8
// 310.600 us; speedup vs baseline: 2.3902x; 1.0106x over previous
//
#include <hip/hip_runtime.h>
#include <hip/hip_bf16.h>

#define TT 2048
#define DM 2048
#define NH 16
#define KVH 4
#define HD 128

typedef __attribute__((ext_vector_type(8))) short bs8;
typedef __attribute__((ext_vector_type(4))) float fx4;
typedef __attribute__((ext_vector_type(4))) unsigned short us4;
typedef __attribute__((ext_vector_type(8))) unsigned short us8;

__device__ inline unsigned short f2b(float f) {
  __hip_bfloat16 h = __float2bfloat16(f);
  return *reinterpret_cast<unsigned short*>(&h);
}

__device__ inline float b2f(unsigned short u) {
  unsigned int v = ((unsigned int)u) << 16;
  return *reinterpret_cast<float*>(&v);
}

__device__ inline void gld_lds16(const ushort* g, ushort* l) {
  __builtin_amdgcn_global_load_lds(
      (const __attribute__((address_space(1))) void*)g,
      (__attribute__((address_space(3))) void*)l,
      16, 0, 0);
}

// ---------------- prep: weight transposes + x cast, one dispatch ----------------
// z=0: Wqkvt[3072][2048] from Wq|Wk|Wv   z=1: Wot[2048][2048] from Wo
// z=2: x fp32 -> bf16 cast (linear)
__global__ __launch_bounds__(256) void prep_kernel(
    const float* __restrict__ x, const float* __restrict__ Wq,
    const float* __restrict__ Wk, const float* __restrict__ Wv,
    const float* __restrict__ Wo, ushort* __restrict__ xb,
    ushort* __restrict__ Wqkvt, ushort* __restrict__ Wot) {
  int tx = threadIdx.x, ty = threadIdx.y;  // block (32,8)
  if (blockIdx.z == 2) {
    int lin = (blockIdx.y * 96 + blockIdx.x) * 256 + ty * 32 + tx;
#pragma unroll
    for (int it = 0; it < 2; ++it) {
      int i = lin + it * (6144 * 256);
      if (i < (TT * 2 * DM) / 4) {
        float4 v = ((const float4*)x)[i];
        us4 o = {f2b(v.x), f2b(v.y), f2b(v.z), f2b(v.w)};
        ((us4*)xb)[i] = o;
      }
    }
    return;
  }
  __shared__ float t[32][33];
  int n0 = blockIdx.x * 32, k0 = blockIdx.y * 32;
  if (blockIdx.z == 0) {
    const float* src;
    int srcN, col0;
    if (n0 < 2048) { src = Wq; srcN = 2048; col0 = n0; }
    else if (n0 < 2560) { src = Wk; srcN = 512; col0 = n0 - 2048; }
    else { src = Wv; srcN = 512; col0 = n0 - 2560; }
    for (int jj = 0; jj < 4; ++jj)
      t[ty + jj * 8][tx] = src[(size_t)(k0 + ty + jj * 8) * srcN + col0 + tx];
    __syncthreads();
    for (int jj = 0; jj < 4; ++jj)
      Wqkvt[(size_t)(n0 + ty + jj * 8) * 2048 + k0 + tx] = f2b(t[tx][ty + jj * 8]);
  } else {
    if (n0 >= 2048) return;
    for (int jj = 0; jj < 4; ++jj)
      t[ty + jj * 8][tx] = Wo[(size_t)(k0 + ty + jj * 8) * 2048 + n0 + tx];
    __syncthreads();
    for (int jj = 0; jj < 4; ++jj)
      Wot[(size_t)(n0 + ty + jj * 8) * 2048 + k0 + tx] = f2b(t[tx][ty + jj * 8]);
  }
}

// ---------------- fused QKV GEMM: [4096 x 3072] = xb * Wqkvt^T ----------------
// LDS-transpose epilogue: q rowmajor, k [b,g,t,d], v NATURAL [b,g,t,d] (vtmp)
#define EPI_STRIDE 136  // shorts; 272 B rows -> 16B-aligned us8 chunks
__global__ __launch_bounds__(256) void gemm_qkv(const ushort* __restrict__ A,
                                                const ushort* __restrict__ Bt,
                                                ushort* __restrict__ qo,
                                                ushort* __restrict__ ko,
                                                ushort* __restrict__ vo,
                                                int K) {
  __shared__ alignas(16) ushort smem[128 * EPI_STRIDE];
  ushort* As = smem;          // 128*64
  ushort* Bs = smem + 8192;   // 128*64
  const int tid = threadIdx.x;
  const int lane = tid & 63;
  const int wid = tid >> 6;
  const int wm = wid >> 1, wn = wid & 1;
  const int quad = lane >> 4, l16 = lane & 15;
  const int bm = blockIdx.y * 128, bn = blockIdx.x * 128;

  fx4 acc[4][4];
  for (int i = 0; i < 4; ++i)
    for (int j = 0; j < 4; ++j) acc[i][j] = (fx4){0.f, 0.f, 0.f, 0.f};

  const int r8 = lane >> 3, s8 = lane & 7;
  for (int k0 = 0; k0 < K; k0 += 64) {
    for (int i = 0; i < 4; ++i) {
      int m = i * 32 + wid * 8 + r8;
      int c = s8 ^ (m & 7);
      gld_lds16(A + (size_t)(bm + m) * K + k0 + c * 8, As + (i * 32 + wid * 8) * 64);
      gld_lds16(Bt + (size_t)(bn + m) * K + k0 + c * 8, Bs + (i * 32 + wid * 8) * 64);
    }
    __syncthreads();
    for (int ks = 0; ks < 2; ++ks) {
      bs8 af[4], bf[4];
      for (int mt = 0; mt < 4; ++mt) {
        int m = wm * 64 + mt * 16 + l16;
        int c = ks * 4 + quad;
        int slot = c ^ (m & 7);
        af[mt] = *(const bs8*)(As + m * 64 + slot * 8);
      }
      for (int nt = 0; nt < 4; ++nt) {
        int n = wn * 64 + nt * 16 + l16;
        int c = ks * 4 + quad;
        int slot = c ^ (n & 7);
        bf[nt] = *(const bs8*)(Bs + n * 64 + slot * 8);
      }
      for (int mt = 0; mt < 4; ++mt)
        for (int nt = 0; nt < 4; ++nt)
          acc[mt][nt] = __builtin_amdgcn_mfma_f32_16x16x32_bf16(af[mt], bf[nt],
                                                                acc[mt][nt], 0, 0, 0);
    }
    __syncthreads();
  }

  // ---- epilogue: C tile -> LDS (bf16), read back row-major, 16B stores ----
  for (int mt = 0; mt < 4; ++mt)
    for (int nt = 0; nt < 4; ++nt)
      for (int r = 0; r < 4; ++r) {
        int row = wm * 64 + mt * 16 + quad * 4 + r;
        int col = wn * 64 + nt * 16 + l16;
        smem[row * EPI_STRIDE + col] = f2b(acc[mt][nt][r]);
      }
  __syncthreads();
  const int rsel = tid >> 4;   // 0..15
  const int csel = tid & 15;   // 16B chunk within row
  for (int ii = 0; ii < 8; ++ii) {
    int row = ii * 16 + rsel;
    us8 chunk = *(const us8*)(smem + row * EPI_STRIDE + csel * 8);
    int row_g = bm + row;
    int colc = bn + csel * 8;
    if (bn < 2048) {
      *(us8*)(qo + (size_t)row_g * 2048 + colc) = chunk;
    } else {
      int b = row_g >> 11, t = row_g & 2047;
      if (bn < 2560) {
        int kc = colc - 2048;
        int gg = kc >> 7, d = kc & 127;
        *(us8*)(ko + ((size_t)(b * KVH + gg) * TT + t) * HD + d) = chunk;
      } else {
        int vc = colc - 2560;
        int gg = vc >> 7, d = vc & 127;
        *(us8*)(vo + ((size_t)(b * KVH + gg) * TT + t) * HD + d) = chunk;
      }
    }
  }
}

// ---------------- transpose V: [b,g,t,d] -> [b,g,d,t] ----------------
__global__ __launch_bounds__(256) void transpose_v(const ushort* __restrict__ vin,
                                                   ushort* __restrict__ vout) {
  __shared__ ushort tl[32][33];
  int tx = threadIdx.x, ty = threadIdx.y;  // (32,8)
  int t0 = blockIdx.x * 32, d0 = blockIdx.y * 32;
  size_t base = (size_t)blockIdx.z * TT * HD;
  for (int jj = 0; jj < 4; ++jj)
    tl[ty + jj * 8][tx] = vin[base + (size_t)(t0 + ty + jj * 8) * HD + d0 + tx];
  __syncthreads();
  for (int jj = 0; jj < 4; ++jj)
    vout[base + (size_t)(d0 + ty + jj * 8) * TT + t0 + tx] = tl[tx][ty + jj * 8];
}

// ---------------- output-projection GEMM: fp32 out ----------------
__global__ __launch_bounds__(256) void gemm_out(const ushort* __restrict__ A,
                                                const ushort* __restrict__ Bt,
                                                float* __restrict__ Cout,
                                                int N, int K) {
  __shared__ alignas(16) ushort smem[128 * EPI_STRIDE];
  ushort* As = smem;
  ushort* Bs = smem + 8192;
  const int tid = threadIdx.x;
  const int lane = tid & 63;
  const int wid = tid >> 6;
  const int wm = wid >> 1, wn = wid & 1;
  const int quad = lane >> 4, l16 = lane & 15;
  const int bm = blockIdx.y * 128, bn = blockIdx.x * 128;

  fx4 acc[4][4];
  for (int i = 0; i < 4; ++i)
    for (int j = 0; j < 4; ++j) acc[i][j] = (fx4){0.f, 0.f, 0.f, 0.f};

  const int r8 = lane >> 3, s8 = lane & 7;
  for (int k0 = 0; k0 < K; k0 += 64) {
    for (int i = 0; i < 4; ++i) {
      int m = i * 32 + wid * 8 + r8;
      int c = s8 ^ (m & 7);
      gld_lds16(A + (size_t)(bm + m) * K + k0 + c * 8, As + (i * 32 + wid * 8) * 64);
      gld_lds16(Bt + (size_t)(bn + m) * K + k0 + c * 8, Bs + (i * 32 + wid * 8) * 64);
    }
    __syncthreads();
    for (int ks = 0; ks < 2; ++ks) {
      bs8 af[4], bf[4];
      for (int mt = 0; mt < 4; ++mt) {
        int m = wm * 64 + mt * 16 + l16;
        int c = ks * 4 + quad;
        int slot = c ^ (m & 7);
        af[mt] = *(const bs8*)(As + m * 64 + slot * 8);
      }
      for (int nt = 0; nt < 4; ++nt) {
        int n = wn * 64 + nt * 16 + l16;
        int c = ks * 4 + quad;
        int slot = c ^ (n & 7);
        bf[nt] = *(const bs8*)(Bs + n * 64 + slot * 8);
      }
      for (int mt = 0; mt < 4; ++mt)
        for (int nt = 0; nt < 4; ++nt)
          acc[mt][nt] = __builtin_amdgcn_mfma_f32_16x16x32_bf16(af[mt], bf[nt],
                                                                acc[mt][nt], 0, 0, 0);
    }
    __syncthreads();
  }

  // ---- epilogue: bf16 LDS round-trip, fp32 vector stores ----
  for (int mt = 0; mt < 4; ++mt)
    for (int nt = 0; nt < 4; ++nt)
      for (int r = 0; r < 4; ++r) {
        int row = wm * 64 + mt * 16 + quad * 4 + r;
        int col = wn * 64 + nt * 16 + l16;
        smem[row * EPI_STRIDE + col] = f2b(acc[mt][nt][r]);
      }
  __syncthreads();
  const int rsel = tid >> 4;
  const int csel = tid & 15;
  for (int ii = 0; ii < 8; ++ii) {
    int row = ii * 16 + rsel;
    us8 chunk = *(const us8*)(smem + row * EPI_STRIDE + csel * 8);
    int row_g = bm + row;
    int colc = bn + csel * 8;
    float4 lo = {b2f(chunk[0]), b2f(chunk[1]), b2f(chunk[2]), b2f(chunk[3])};
    float4 hi = {b2f(chunk[4]), b2f(chunk[5]), b2f(chunk[6]), b2f(chunk[7])};
    *(float4*)(Cout + (size_t)row_g * N + colc) = lo;
    *(float4*)(Cout + (size_t)row_g * N + colc + 4) = hi;
  }
}

// ---------------- fused causal WGQA attention, 8-wave blocks ----------------
// 512 blocks x 512 threads. Block = 128-query chunk; wave owns 16 queries.
// Complementary qt mapping keeps per-CU iteration count uniform (34) and the
// two co-resident blocks hide each other's staging latency. 16 waves/CU.
__global__ __launch_bounds__(512, 4) void attn_kernel(const ushort* __restrict__ qb,
                                                      const ushort* __restrict__ kb,
                                                      const ushort* __restrict__ vt,
                                                      ushort* __restrict__ yb,
                                                      const float* __restrict__ wlog) {
  __shared__ alignas(16) ushort Ks[64 * 128];   // [key][d], chunk-swizzled
  __shared__ alignas(16) ushort Vs[128 * 64];   // [d][key], chunk-swizzled
  __shared__ alignas(16) ushort Ps[128 * 72];   // [q][key], stride 72 (pad)

  const int bid = blockIdx.x;
  const int qt = (bid & 256) ? (bid & 15) : 15 - (bid & 15);
  const int h = (bid >> 4) & 15;
  const int b = bid >> 8;
  const int g = h >> 2;
  const int tid = threadIdx.x;
  const int lane = tid & 63;
  const int wid = tid >> 6;        // 0..7
  const int quad = lane >> 4;
  const int l16 = lane & 15;
  const int qw = qt * 128 + wid * 16;   // wave's first query

  const float scale = wlog[g] * 0.08838834764831845f;  // 1/sqrt(128)

  // Q fragments in registers (B-operand of S^T = K * Q^T)
  bs8 qf[4];
  {
    int q = qw + l16;
    const ushort* qrow = qb + ((size_t)(b * TT + q)) * DM + h * HD;
#pragma unroll
    for (int ks = 0; ks < 4; ++ks)
      qf[ks] = *(const bs8*)(qrow + ks * 32 + quad * 8);
  }

  float m_i = -INFINITY;  // running max of RAW logits
  float l_i = 0.f;
  fx4 o[8];
#pragma unroll
  for (int i = 0; i < 8; ++i) o[i] = (fx4){0.f, 0.f, 0.f, 0.f};

  const ushort* kbase = kb + (size_t)(b * KVH + g) * TT * HD;
  const ushort* vbase = vt + (size_t)(b * KVH + g) * HD * TT;

  // persistent staging pointers; each thread stages 2 K-slots + 2 V-slots
  const ushort* kp;
  const ushort* vp;
  {
    int keyr = wid * 4 + (lane >> 4);          // 0..31
    int si = lane & 15;
    int ck = (si & 8) | ((si ^ keyr) & 7);
    kp = kbase + (size_t)keyr * HD + ck * 8;
    int dr = wid * 8 + (lane >> 3);            // 0..63
    int s8 = lane & 7;
    int cv = s8 ^ (dr & 7);
    vp = vbase + (size_t)dr * TT + cv * 8;
  }

  const int jmax = 2 * qt + 1;
  for (int j = 0; j <= jmax; ++j) {
    // ---- stage K tile (64x128) and V^T tile (128x64): 4 lds-DMAs/thread ----
    gld_lds16(kp, Ks + wid * 512);               // K rows wid*4   .. +3
    gld_lds16(kp + 32 * HD, Ks + 4096 + wid * 512);  // K rows 32+wid*4
    gld_lds16(vp, Vs + wid * 512);               // V rows wid*8   .. +7
    gld_lds16(vp + 64 * TT, Vs + 4096 + wid * 512);  // V rows 64+wid*8
    kp += 64 * HD;
    vp += 64;
    __syncthreads();

    if (j * 64 <= qw + 15) {  // wave has at least one unmasked key
      // ---- S^T = K * Q^T  (64 keys x 16 queries), fp32 acc ----
      fx4 s[4];
#pragma unroll
      for (int mt = 0; mt < 4; ++mt) s[mt] = (fx4){0.f, 0.f, 0.f, 0.f};
#pragma unroll
      for (int mt = 0; mt < 4; ++mt) {
        bs8 a[4];
        int key = mt * 16 + l16;
#pragma unroll
        for (int ks = 0; ks < 4; ++ks) {
          int c = ks * 4 + quad;
          int slot = (c & 8) | ((c ^ key) & 7);
          a[ks] = *(const bs8*)(Ks + key * 128 + slot * 8);
        }
#pragma unroll
        for (int ks = 0; ks < 4; ++ks)
          s[mt] = __builtin_amdgcn_mfma_f32_16x16x32_bf16(a[ks], qf[ks],
                                                          s[mt], 0, 0, 0);
      }

      // ---- causal mask: needed iff tile max key > wave min query ----
      const int q = qw + l16;
      if (j * 64 + 63 > qw) {
#pragma unroll
        for (int mt = 0; mt < 4; ++mt)
#pragma unroll
          for (int r = 0; r < 4; ++r) {
            int key = j * 64 + mt * 16 + quad * 4 + r;
            if (key > q) s[mt][r] = -1e30f;
          }
      }
      float mx = s[0][0];
#pragma unroll
      for (int mt = 0; mt < 4; ++mt)
#pragma unroll
        for (int r = 0; r < 4; ++r) mx = fmaxf(mx, s[mt][r]);
      mx = fmaxf(mx, __shfl_xor(mx, 16));
      mx = fmaxf(mx, __shfl_xor(mx, 32));
      float m_new = fmaxf(m_i, mx);
      float alpha = __expf((m_i - m_new) * scale);
      float negb = -m_new * scale;
      float sum = 0.f;
#pragma unroll
      for (int mt = 0; mt < 4; ++mt)
#pragma unroll
        for (int r = 0; r < 4; ++r) {
          float pv = __expf(fmaf(s[mt][r], scale, negb));
          s[mt][r] = pv;
          sum += pv;
        }
      sum += __shfl_xor(sum, 16);
      sum += __shfl_xor(sum, 32);
      l_i = l_i * alpha + sum;
      m_i = m_new;
#pragma unroll
      for (int dmt = 0; dmt < 8; ++dmt)
#pragma unroll
        for (int r = 0; r < 4; ++r) o[dmt][r] *= alpha;

      // P (bf16) to LDS in [q][key] layout; wave touches only its 16 rows
      int qrow = wid * 16 + l16;
#pragma unroll
      for (int mt = 0; mt < 4; ++mt) {
        us4 pw = {f2b(s[mt][0]), f2b(s[mt][1]), f2b(s[mt][2]), f2b(s[mt][3])};
        *(us4*)(Ps + qrow * 72 + mt * 16 + quad * 4) = pw;
      }

      // ---- O^T += V^T * P^T  (no barrier: wave reads only its own P rows) ----
#pragma unroll
      for (int ks = 0; ks < 2; ++ks) {
        bs8 pb = *(const bs8*)(Ps + qrow * 72 + ks * 32 + quad * 8);
#pragma unroll
        for (int dmt = 0; dmt < 8; ++dmt) {
          int d = dmt * 16 + l16;
          int c = ks * 4 + quad;
          int slot = c ^ (d & 7);
          bs8 va = *(const bs8*)(Vs + d * 64 + slot * 8);
          o[dmt] = __builtin_amdgcn_mfma_f32_16x16x32_bf16(va, pb, o[dmt], 0, 0, 0);
        }
      }
    }
    __syncthreads();
  }

  // ---- epilogue: normalize and write y (bf16, [b][t][h*128+d]) ----
  {
    float inv = 1.0f / l_i;
    int q = qw + l16;
    ushort* yrow = yb + ((size_t)(b * TT + q)) * DM + h * HD;
#pragma unroll
    for (int dmt = 0; dmt < 8; ++dmt) {
      us4 w = {f2b(o[dmt][0] * inv), f2b(o[dmt][1] * inv),
               f2b(o[dmt][2] * inv), f2b(o[dmt][3] * inv)};
      *(us4*)(yrow + dmt * 16 + quad * 4) = w;
    }
  }
}

// ---------------- launch ----------------
extern "C" void kernel_launch(void* const* d_in, const int* in_sizes, int n_in,
                              void* d_out, int out_size, void* d_ws, size_t ws_size,
                              hipStream_t stream) {
  const float* x = (const float*)d_in[0];
  // d_in[1] = attn_mask: ignored (exact causal mask computed analytically)
  const float* Wq = (const float*)d_in[2];
  const float* Wk = (const float*)d_in[3];
  const float* Wv = (const float*)d_in[4];
  const float* Wo = (const float*)d_in[5];
  const float* wlog = (const float*)d_in[6];
  // d_in[7] = weight_values: unused by the reference

  char* ws = (char*)d_ws;
  ushort* xb = (ushort*)ws;     ws += (size_t)4096 * 2048 * 2;
  ushort* Wqkvt = (ushort*)ws;  ws += (size_t)3072 * 2048 * 2;
  ushort* Wot = (ushort*)ws;    ws += (size_t)2048 * 2048 * 2;
  ushort* qbuf = (ushort*)ws;   ws += (size_t)4096 * 2048 * 2;
  ushort* kbuf = (ushort*)ws;   ws += (size_t)2 * KVH * 2048 * 128 * 2;
  ushort* vtmp = (ushort*)ws;   ws += (size_t)2 * KVH * 2048 * 128 * 2;
  ushort* vbuf = (ushort*)ws;   ws += (size_t)2 * KVH * 2048 * 128 * 2;
  ushort* ybuf = (ushort*)ws;   ws += (size_t)4096 * 2048 * 2;

  prep_kernel<<<dim3(96, 64, 3), dim3(32, 8), 0, stream>>>(
      x, Wq, Wk, Wv, Wo, xb, Wqkvt, Wot);
  gemm_qkv<<<dim3(24, 32), 256, 0, stream>>>(xb, Wqkvt, qbuf, kbuf, vtmp, 2048);
  transpose_v<<<dim3(64, 4, 8), dim3(32, 8), 0, stream>>>(vtmp, vbuf);
  attn_kernel<<<512, 512, 0, stream>>>(qbuf, kbuf, vbuf, ybuf, wlog);
  gemm_out<<<dim3(16, 32), 256, 0, stream>>>(ybuf, Wot, (float*)d_out, 2048, 2048);
}